// Round 1
// baseline (52.414 us; speedup 1.0000x reference)
//
#include <hip/hip_runtime.h>

// Problem constants (fixed by setup_inputs):
//   x: (64,1,8,8) f32; KH=KW=5 -> oh=ow=4 -> N = 64*16 = 1024 rows, 25 feats/row
//   idx0:(128,36,6) in [0,25), lut0:(128,36,64)
//   idx1:(128, 6,6) in [0,36), lut1:(128, 6,64)
//   idx2:(128, 1,6) in [0, 6), lut2:(128, 1,64)
//   out: (64,128,4,4) f32 = 131072 elems
#define T_TREES 128
#define M0 36
#define M1 6
#define NNODES (M0 + M1 + 1)   // 43
#define NTHREADS 128
#define NROWS 1024

// One soft-LUT node: h = sum_{p,q,r} P[p*16+q*4+r] * Wa[p] * Wb[q] * Wc[r]
// with Wa = [ (1-a)(1-b), (1-a)b, a(1-b), ab ] etc.
// sl points at 64 sigmoided LUT values in LDS (wave-uniform address).
__device__ __forceinline__ float lut_node(const float* sl,
                                          float a, float b, float c,
                                          float d, float e, float f) {
    float wa[4] = {(1.f - a) * (1.f - b), (1.f - a) * b, a * (1.f - b), a * b};
    float wb[4] = {(1.f - c) * (1.f - d), (1.f - c) * d, c * (1.f - d), c * d};
    float wc[4] = {(1.f - e) * (1.f - f), (1.f - e) * f, e * (1.f - f), e * f};
    float acc = 0.f;
#pragma unroll
    for (int p = 0; p < 4; ++p) {
        float tp = 0.f;
#pragma unroll
        for (int q = 0; q < 4; ++q) {
            const float4 P = *reinterpret_cast<const float4*>(sl + p * 16 + q * 4);
            float tq = P.x * wc[0] + P.y * wc[1] + P.z * wc[2] + P.w * wc[3];
            tp += tq * wb[q];
        }
        acc += tp * wa[p];
    }
    return acc;
}

__global__ __launch_bounds__(NTHREADS) void clut_kernel(
    const float* __restrict__ x,
    const int* __restrict__ idx0, const float* __restrict__ lut0,
    const int* __restrict__ idx1, const float* __restrict__ lut1,
    const int* __restrict__ idx2, const float* __restrict__ lut2,
    float* __restrict__ out) {
    // LDS: sigmoided LUTs (uniform broadcast reads) + per-thread columns
    // (runtime-indexed gathers must live in LDS, not registers — layout
    // [k][tid] makes bank = tid%32, conflict-free).
    __shared__ __align__(16) float slut[NNODES * 64];   // 11008 B
    __shared__ float feat[25 * NTHREADS];               // 12800 B
    __shared__ float h0[M0 * NTHREADS];                 // 18432 B
    __shared__ float h1[M1 * NTHREADS];                 //  3072 B

    const int tid = threadIdx.x;
    const int t = blockIdx.y;

    // ---- stage sigmoid(lut) for this tree ----
    for (int i = tid; i < NNODES * 64; i += NTHREADS) {
        float v;
        if (i < M0 * 64)                v = lut0[t * (M0 * 64) + i];
        else if (i < (M0 + M1) * 64)    v = lut1[t * (M1 * 64) + (i - M0 * 64)];
        else                            v = lut2[t * 64 + (i - (M0 + M1) * 64)];
        slut[i] = 1.f / (1.f + __expf(-v));
    }

    // ---- per-thread features: feat[n][i*5+j] = x[b, (i+y), (j+xx)] ----
    const int n = blockIdx.x * NTHREADS + tid;   // row id in [0,1024)
    const int b = n >> 4;
    const int s = n & 15;
    const int yy = s >> 2;
    const int xx = s & 3;
    const float* xb = x + b * 64 + yy * 8 + xx;
#pragma unroll
    for (int i = 0; i < 5; ++i)
#pragma unroll
        for (int j = 0; j < 5; ++j)
            feat[(i * 5 + j) * NTHREADS + tid] = xb[i * 8 + j];

    __syncthreads();   // slut ready (feat/h0/h1 are thread-private columns)

    // ---- layer 0: 36 nodes over 25 features ----
    for (int m = 0; m < M0; ++m) {
        const int* id = idx0 + (t * M0 + m) * 6;
        float a = feat[id[0] * NTHREADS + tid];
        float bb = feat[id[1] * NTHREADS + tid];
        float c = feat[id[2] * NTHREADS + tid];
        float d = feat[id[3] * NTHREADS + tid];
        float e = feat[id[4] * NTHREADS + tid];
        float f = feat[id[5] * NTHREADS + tid];
        h0[m * NTHREADS + tid] = lut_node(slut + m * 64, a, bb, c, d, e, f);
    }

    // ---- layer 1: 6 nodes over 36 ----
    for (int m = 0; m < M1; ++m) {
        const int* id = idx1 + (t * M1 + m) * 6;
        float a = h0[id[0] * NTHREADS + tid];
        float bb = h0[id[1] * NTHREADS + tid];
        float c = h0[id[2] * NTHREADS + tid];
        float d = h0[id[3] * NTHREADS + tid];
        float e = h0[id[4] * NTHREADS + tid];
        float f = h0[id[5] * NTHREADS + tid];
        h1[m * NTHREADS + tid] = lut_node(slut + (M0 + m) * 64, a, bb, c, d, e, f);
    }

    // ---- layer 2: 1 node over 6 ----
    {
        const int* id = idx2 + t * 6;
        float a = h1[id[0] * NTHREADS + tid];
        float bb = h1[id[1] * NTHREADS + tid];
        float c = h1[id[2] * NTHREADS + tid];
        float d = h1[id[3] * NTHREADS + tid];
        float e = h1[id[4] * NTHREADS + tid];
        float f = h1[id[5] * NTHREADS + tid];
        float o = lut_node(slut + (M0 + M1) * 64, a, bb, c, d, e, f);
        // out[b, t, s] with s = yy*4+xx
        out[b * (T_TREES * 16) + t * 16 + s] = o;
    }
}

extern "C" void kernel_launch(void* const* d_in, const int* in_sizes, int n_in,
                              void* d_out, int out_size, void* d_ws, size_t ws_size,
                              hipStream_t stream) {
    const float* x    = (const float*)d_in[0];
    const int*   idx0 = (const int*)  d_in[1];
    const float* lut0 = (const float*)d_in[2];
    const int*   idx1 = (const int*)  d_in[3];
    const float* lut1 = (const float*)d_in[4];
    const int*   idx2 = (const int*)  d_in[5];
    const float* lut2 = (const float*)d_in[6];
    float* out = (float*)d_out;

    dim3 grid(NROWS / NTHREADS, T_TREES);   // (8, 128)
    clut_kernel<<<grid, NTHREADS, 0, stream>>>(x, idx0, lut0, idx1, lut1,
                                               idx2, lut2, out);
}